// Round 7
// baseline (1500.137 us; speedup 1.0000x reference)
//
#include <hip/hip_runtime.h>
#include <hip/hip_bf16.h>

// GroupedExperts: out[t] = (silu(x@w1[e]^T) * (x@w3[e]^T)) @ w2[e]^T
// E=8, T=16384, D=2048, H=5632; tokens pre-sorted by expert, even split.
//
// Round 7: exact m201 quadrant schedule. 256x256 tile, BK=64, 8 waves
// (2Mx4N), 2-buf LDS (128-B rows, 8-slot XOR swizzle phys=slot^(row&7)).
// Per K-tile 4 phases with reads {12,4,8,0} (quadrant order Q1 m0-3/n0-1,
// Q2 m0-3/n2-3, Q3 m4-7/n2-3, Q4 m4-7/n0-1; A reused 2 phases, B-lo live
// Q1->Q4, B-hi Q2->Q3 in regs). Stages: Q1 A0(t+1), Q2 A1(t+1),
// Q3 B0(t+2), Q4 B1(t+2); ONE vmcnt(4) per tile at Q4 (stage->wait >= 2
// phases, stage->read 3-6 phases). lgkmcnt(8) throttle in the 12-read
// phase. Full write-after-read ledger verified (A region free after Q3,
// B after Q2). gate/up fused via 16-row w13 interleave.

typedef __bf16 bf16x8 __attribute__((ext_vector_type(8)));
typedef float f32x4 __attribute__((ext_vector_type(4)));
typedef unsigned short u16x8 __attribute__((ext_vector_type(8)));

constexpr int E = 8;
constexpr int T = 16384;
constexpr int D = 2048;
constexpr int H = 5632;

#define DEV static __device__ __forceinline__

DEV unsigned short f2bf(float f) {
    unsigned u = __builtin_bit_cast(unsigned, f);
    u = (u + 0x7FFFu + ((u >> 16) & 1u)) >> 16;   // RNE
    return (unsigned short)u;
}

DEV void gload16(const void* g, void* l) {
    __builtin_amdgcn_global_load_lds(
        (const __attribute__((address_space(1))) void*)g,
        (__attribute__((address_space(3))) void*)l, 16, 0, 0);
}

DEV f32x4 mfma16(bf16x8 a, bf16x8 b, f32x4 c) {
    return __builtin_amdgcn_mfma_f32_16x16x32_bf16(a, b, c, 0, 0, 0);
}

DEV void cvt8(const float* src, unsigned short* dst) {
    float4 a = *(const float4*)src;
    float4 c = *(const float4*)(src + 4);
    u16x8 r;
    r[0] = f2bf(a.x); r[1] = f2bf(a.y); r[2] = f2bf(a.z); r[3] = f2bf(a.w);
    r[4] = f2bf(c.x); r[5] = f2bf(c.y); r[6] = f2bf(c.z); r[7] = f2bf(c.w);
    *(u16x8*)dst = r;
}

// ------- merged pre-GEMM converts: x (linear) + w1/w3 (interleave-16) -----
// w13b[e] row layout: rr = (h>>4)*32 + which*16 + (h&15); which 0=w1, 1=w3.
__global__ __launch_bounds__(256) void k_cvt_pre(
    const float* __restrict__ x, const float* __restrict__ w1,
    const float* __restrict__ w3, unsigned short* __restrict__ xb,
    unsigned short* __restrict__ w13b) {
    const int bid = blockIdx.x, tid = threadIdx.x;
    if (bid < 512) {
        const long n8 = (long)T * D / 8;
        for (long i = (long)bid * 256 + tid; i < n8; i += 512L * 256)
            cvt8(x + i * 8, xb + i * 8);
    } else {
        const int which = (bid < 1280) ? 0 : 1;
        const float* src = which ? w3 : w1;
        const long b0 = which ? 1280 : 512;
        const long n8 = (long)E * H * D / 8;
        for (long i = ((long)bid - b0) * 256 + tid; i < n8; i += 768L * 256) {
            int col8 = (int)(i & 255);          // D/8 = 256
            int rowi = (int)(i >> 8);           // e*H + h
            int e = rowi / H;
            int h = rowi - e * H;
            int rr = ((h >> 4) << 5) + (which << 4) + (h & 15);
            cvt8(src + i * 8,
                 w13b + ((size_t)e * (2 * H) + rr) * D + (size_t)col8 * 8);
        }
    }
}

// linear cvt (w2)
__global__ __launch_bounds__(256) void k_cvt(const float* __restrict__ in,
                                             unsigned short* __restrict__ out,
                                             long n8) {
    long i = (long)blockIdx.x * blockDim.x + threadIdx.x;
    long stride = (long)gridDim.x * blockDim.x;
    for (; i < n8; i += stride) cvt8(in + i * 8, out + i * 8);
}

// ---------------- expert lookup for a row tile ----------------------------
DEV int expert_of_row(const int* __restrict__ ntp, int row0) {
    int e = 0, s = 0;
    for (int i = 0; i < E; ++i) {
        int c = ntp[i];
        if (row0 < s + c) { e = i; break; }
        s += c;
    }
    return e;
}

// ---------------- 256x256 BK=64 quadrant-schedule GEMM core ---------------
// 512 thr = 8 waves (2M x 4N); wave out 128x64 = acc[8][4] f32x4.
// LDS per operand: 2 buf x 256 rows x 64 el (128-B rows) = 64 KiB.
// Swizzle: 16-B slot s of row r stored at s ^ (r&7); inverse on the global
// staging source (per-lane constant), linear global_load_lds dest.
// Stage unit = half-M x BK (128x64 = 16 KB = 2 gloads/thread).
template <int LD, int NT>
DEV void gemm_q(const unsigned short* pa, const unsigned short* pb,
                unsigned short* sA, unsigned short* sB, int tid,
                f32x4 (&acc)[8][4]) {
    const int lane = tid & 63, wid = tid >> 6;
    const int wm = wid >> 2, wn = wid & 3;

    // read constants (ushort units)
    const int s0 = ((lane >> 4) ^ (lane & 7)) << 3;   // kk0 slot; kk1 = ^32
    const int rA = (wm * 128 + (lane & 15)) * 64;
    const int rB = (wn * 64 + (lane & 15)) * 64;

    char* cA = (char*)sA;
    char* cB = (char*)sB;
    const int dW = wid << 10;

    auto stage = [&](char* base, const unsigned short* g, int h, int bbB) {
        char* l = base + bbB + (h << 14) + dW;
        const unsigned short* gs = g + (size_t)h * 128 * LD;
        gload16(gs, l);
        gload16(gs + (size_t)64 * LD, l + 8192);
    };

    bf16x8 a[4][2], blo[2][2], bhi[2][2];

    auto rdA = [&](int boU, int mb) {
        const unsigned short* P = sA + boU + rA + (mb << 12);
#pragma unroll
        for (int m = 0; m < 4; ++m) {
            a[m][0] = *(const bf16x8*)(P + m * 1024 + s0);
            a[m][1] = *(const bf16x8*)(P + m * 1024 + (s0 ^ 32));
        }
    };
    auto rdB = [&](bf16x8 (&b)[2][2], int boU, int nb) {
        const unsigned short* P = sB + boU + rB + (nb << 11);
#pragma unroll
        for (int n = 0; n < 2; ++n) {
            b[n][0] = *(const bf16x8*)(P + n * 1024 + s0);
            b[n][1] = *(const bf16x8*)(P + n * 1024 + (s0 ^ 32));
        }
    };
    auto MM = [&](bf16x8 (&b)[2][2], int mb, int nb) {
#pragma unroll
        for (int m = 0; m < 4; ++m)
#pragma unroll
            for (int n = 0; n < 2; ++n) {
                f32x4 c = acc[mb * 4 + m][nb * 2 + n];
                c = mfma16(a[m][0], b[n][0], c);
                c = mfma16(a[m][1], b[n][1], c);
                acc[mb * 4 + m][nb * 2 + n] = c;
            }
    };

    // prologue: tile0 (4 halves) + B halves of tile1; vmcnt(4) keeps B(1).
    stage(cA, pa, 0, 0); stage(cA, pa, 1, 0);
    stage(cB, pb, 0, 0); stage(cB, pb, 1, 0);
    stage(cB, pb + 64, 0, 32768); stage(cB, pb + 64, 1, 32768);
    asm volatile("s_waitcnt vmcnt(4)" ::: "memory");
    __builtin_amdgcn_s_barrier();

    const unsigned short* pA1 = pa + 64;    // A source for tile t+1
    const unsigned short* pB2 = pb + 128;   // B source for tile t+2

#pragma unroll 1
    for (int t = 0; t < NT; ++t) {
        const int boU = (t & 1) << 14;      // ushort offset of current buf
        const int boB = boU << 1;           // bytes
        const int nbB = boB ^ 32768;
        const bool s1ok = (t + 1 < NT), s2ok = (t + 2 < NT);

        // ===== Q1: rd 12 (A m0-3 + B lo); stage A0(t+1); mm m0-3 x n0-1
        rdA(boU, 0);
        rdB(blo, boU, 0);
        if (s1ok) stage(cA, pA1, 0, nbB);
        asm volatile("s_waitcnt lgkmcnt(8)" ::: "memory");
        __builtin_amdgcn_s_barrier();
        asm volatile("s_waitcnt lgkmcnt(0)" ::: "memory");
        __builtin_amdgcn_sched_barrier(0);
        __builtin_amdgcn_s_setprio(1); MM(blo, 0, 0);
        __builtin_amdgcn_s_setprio(0);
        __builtin_amdgcn_s_barrier();

        // ===== Q2: rd 4 (B hi); stage A1(t+1); mm m0-3 x n2-3
        rdB(bhi, boU, 1);
        if (s1ok) stage(cA, pA1, 1, nbB);
        __builtin_amdgcn_s_barrier();
        asm volatile("s_waitcnt lgkmcnt(0)" ::: "memory");
        __builtin_amdgcn_sched_barrier(0);
        __builtin_amdgcn_s_setprio(1); MM(bhi, 0, 1);
        __builtin_amdgcn_s_setprio(0);
        __builtin_amdgcn_s_barrier();

        // ===== Q3: rd 8 (A m4-7); stage B0(t+2); mm m4-7 x n2-3
        rdA(boU, 1);
        if (s2ok) stage(cB, pB2, 0, boB);
        __builtin_amdgcn_s_barrier();
        asm volatile("s_waitcnt lgkmcnt(0)" ::: "memory");
        __builtin_amdgcn_sched_barrier(0);
        __builtin_amdgcn_s_setprio(1); MM(bhi, 1, 1);
        __builtin_amdgcn_s_setprio(0);
        __builtin_amdgcn_s_barrier();

        // ===== Q4: rd 0; stage B1(t+2); vmcnt(4); mm m4-7 x n0-1
        if (s2ok) {
            stage(cB, pB2, 1, boB);
            asm volatile("s_waitcnt vmcnt(4)" ::: "memory");
        } else {
            asm volatile("s_waitcnt vmcnt(0)" ::: "memory");
        }
        __builtin_amdgcn_s_barrier();
        __builtin_amdgcn_sched_barrier(0);
        __builtin_amdgcn_s_setprio(1); MM(blo, 1, 0);
        __builtin_amdgcn_s_setprio(0);
        __builtin_amdgcn_s_barrier();

        pA1 += 64; pB2 += 64;
    }
}

// ---------------- kernel 1: fused gate/up grouped GEMM + SwiGLU -----------
// A = xb (T x D), B = w13b[e] (2H x D interleave-16), h (T x H bf16).
__global__ __launch_bounds__(512, 2) void k_gate_up(
    const unsigned short* __restrict__ xb,
    const unsigned short* __restrict__ w13b,
    const int* __restrict__ ntp,
    unsigned short* __restrict__ hbuf) {
    __shared__ unsigned short sA[2 * 16384];
    __shared__ unsigned short sB[2 * 16384];

    const int nwg = gridDim.x;           // 2816
    const int cpx = nwg >> 3;
    const int bid = blockIdx.x;
    const int swz = (bid & 7) * cpx + (bid >> 3);
    const int tm = swz & 63;             // tm fastest: B-panel L2 reuse
    const int tn = swz >> 6;             // 0..43

    const int row0 = tm << 8;
    const int e = expert_of_row(ntp, row0);
    const int tid = threadIdx.x;
    const int lane = tid & 63, wid = tid >> 6;

    // staging sources: row = tid>>3, logical slot = (tid&7)^((tid>>3)&7)
    const int sr = tid >> 3;
    const int sl = (tid & 7) ^ ((tid >> 3) & 7);
    const unsigned short* pa = xb + (size_t)(row0 + sr) * D + sl * 8;
    const unsigned short* pb = w13b + (size_t)e * (2 * H) * D +
                               (size_t)((tn << 8) + sr) * D + sl * 8;

    f32x4 acc[8][4] = {};
    gemm_q<D, D / 64>(pa, pb, sA, sB, tid, acc);

    // Epilogue: ni pairs (0,1),(2,3) = (gate,up). C/D: col=lane&15,
    // row=(lane>>4)*4+j.
    const int wm = wid >> 2, wn = wid & 3;
    const int rbase = row0 + (wm << 7) + ((lane >> 4) << 2);
    const int cb = (((tn << 3) + (wn << 1)) << 4) + (lane & 15);
#pragma unroll
    for (int mi = 0; mi < 8; ++mi)
#pragma unroll
        for (int pi = 0; pi < 2; ++pi) {
            f32x4 g = acc[mi][2 * pi], u = acc[mi][2 * pi + 1];
            const int hcol = cb + (pi << 4);
#pragma unroll
            for (int j = 0; j < 4; ++j) {
                float gv = g[j];
                float hv = gv * u[j] / (1.f + __expf(-gv));
                hbuf[(size_t)(rbase + (mi << 4) + j) * H + hcol] = f2bf(hv);
            }
        }
}

// ---------------- kernel 2: down grouped GEMM -----------------------------
// A = h (T x H), B = w2b[e] (D x H), out (T x D f32). K = H = 5632.
__global__ __launch_bounds__(512, 2) void k_down(
    const unsigned short* __restrict__ hbuf,
    const unsigned short* __restrict__ w2b,
    const int* __restrict__ ntp,
    float* __restrict__ out) {
    __shared__ unsigned short sA[2 * 16384];
    __shared__ unsigned short sB[2 * 16384];

    const int nwg = gridDim.x;           // 512
    const int cpx = nwg >> 3;
    const int bid = blockIdx.x;
    const int swz = (bid & 7) * cpx + (bid >> 3);
    const int tm = swz & 63;
    const int tn = swz >> 6;             // 0..7

    const int row0 = tm << 8;
    const int e = expert_of_row(ntp, row0);
    const int tid = threadIdx.x;
    const int lane = tid & 63, wid = tid >> 6;

    const int sr = tid >> 3;
    const int sl = (tid & 7) ^ ((tid >> 3) & 7);
    const unsigned short* pa = hbuf + (size_t)(row0 + sr) * H + sl * 8;
    const unsigned short* pb = w2b + (size_t)e * D * H +
                               (size_t)((tn << 8) + sr) * H + sl * 8;

    f32x4 acc[8][4] = {};
    gemm_q<H, H / 64>(pa, pb, sA, sB, tid, acc);

    const int wm = wid >> 2, wn = wid & 3;
    const int rbase = row0 + (wm << 7) + ((lane >> 4) << 2);
    const int cb = (tn << 8) + (wn << 6) + (lane & 15);
#pragma unroll
    for (int mi = 0; mi < 8; ++mi)
#pragma unroll
        for (int ni = 0; ni < 4; ++ni) {
            f32x4 c = acc[mi][ni];
#pragma unroll
            for (int j = 0; j < 4; ++j)
                out[(size_t)(rbase + (mi << 4) + j) * D + cb + (ni << 4)] =
                    c[j];
        }
}

extern "C" void kernel_launch(void* const* d_in, const int* in_sizes, int n_in,
                              void* d_out, int out_size, void* d_ws,
                              size_t ws_size, hipStream_t stream) {
    const float* x = (const float*)d_in[0];
    const float* w1 = (const float*)d_in[1];
    const float* w2 = (const float*)d_in[2];
    const float* w3 = (const float*)d_in[3];
    const int* ntp = (const int*)d_in[4];
    float* out = (float*)d_out;

    char* ws = (char*)d_ws;
    // ws layout (bytes):
    //   xb  : [0, 64MiB)                 T*D*2
    //   w13b: [64MiB, 64+352MiB)         E*2H*D*2  (reused for w2b)
    //   h   : [416MiB, 448MiB)           T*H*2
    unsigned short* xb = (unsigned short*)(ws + 0);
    unsigned short* w13b = (unsigned short*)(ws + 67108864L);
    unsigned short* hbuf = (unsigned short*)(ws + 67108864L + 385875968L);
    unsigned short* w2b = w13b;  // dead after k_gate_up

    k_cvt_pre<<<2048, 256, 0, stream>>>(x, w1, w3, xb, w13b);

    k_gate_up<<<(T / 256) * (2 * H / 256), 512, 0, stream>>>(xb, w13b, ntp,
                                                             hbuf);

    k_cvt<<<2048, 256, 0, stream>>>(w2, w2b, (long)E * D * H / 8);

    k_down<<<(T / 256) * (D / 256), 512, 0, stream>>>(hbuf, w2b, ntp, out);
}